// Round 4
// baseline (989.814 us; speedup 1.0000x reference)
//
#include <hip/hip_runtime.h>

#define N_SRC   100000
#define N_DST   100000
#define N_EDGES 1250000
#define D_FEAT  64
#define HIDDEN  64
#define OUT_F   128

// ---------------------------------------------------------------------------
// Kernel 1: hs = relu(h_src @ W1 + b1)   [N_SRC, 64]
// One wave per row: lane j computes output j. W1 staged in LDS (16 KB).
// ---------------------------------------------------------------------------
__global__ __launch_bounds__(256) void fc1_kernel(
        const float* __restrict__ h_src, const float* __restrict__ W1,
        const float* __restrict__ b1, float* __restrict__ hs) {
    __shared__ float W1s[D_FEAT * HIDDEN];
    for (int i = threadIdx.x; i < D_FEAT * HIDDEN; i += 256) W1s[i] = W1[i];
    __syncthreads();
    const int lane = threadIdx.x & 63;
    const int wid  = threadIdx.x >> 6;
    const int row  = blockIdx.x * 4 + wid;
    if (row >= N_SRC) return;
    float x   = h_src[row * D_FEAT + lane];
    float acc = b1[lane];
    #pragma unroll
    for (int k = 0; k < D_FEAT; ++k) {
        float a = __shfl(x, k, 64);
        acc = fmaf(a, W1s[k * HIDDEN + lane], acc);
    }
    hs[row * HIDDEN + lane] = fmaxf(acc, 0.0f);
}

// ---------------------------------------------------------------------------
// CSR build, step 1: histogram of dst (counts written into rowptrA).
// ---------------------------------------------------------------------------
__global__ __launch_bounds__(256) void hist_kernel(
        const int* __restrict__ dst, int* __restrict__ counts) {
    int i = blockIdx.x * blockDim.x + threadIdx.x;
    const int stride = gridDim.x * blockDim.x;
    for (; i < N_EDGES; i += stride) atomicAdd(&counts[dst[i]], 1);
}

// ---------------------------------------------------------------------------
// CSR build, step 2: single-block exclusive scan, in place (counts->rowptr),
// plus a second copy into cursor[] for the scatter pass.
// 1024 threads, each owns a 98-element chunk; Hillis-Steele over partials.
// ---------------------------------------------------------------------------
__global__ __launch_bounds__(1024) void scan_kernel(
        int* __restrict__ rp, int* __restrict__ cursor) {
    __shared__ int part[1024];
    const int t  = threadIdx.x;
    const int CH = (N_DST + 1023) / 1024;            // 98
    const int lo = t * CH;
    const int hi = min(lo + CH, N_DST);
    int s = 0;
    for (int i = lo; i < hi; ++i) s += rp[i];
    part[t] = s;
    __syncthreads();
    for (int off = 1; off < 1024; off <<= 1) {
        int v = part[t];
        int u = (t >= off) ? part[t - off] : 0;
        __syncthreads();
        part[t] = v + u;
        __syncthreads();
    }
    int running = (t == 0) ? 0 : part[t - 1];
    for (int i = lo; i < hi; ++i) {
        int c = rp[i];
        rp[i]     = running;
        cursor[i] = running;
        running  += c;
    }
}

// ---------------------------------------------------------------------------
// CSR build, step 3: scatter (src, weight) pairs into dst-sorted order.
// ---------------------------------------------------------------------------
__global__ __launch_bounds__(256) void scatter_kernel(
        const int* __restrict__ src, const int* __restrict__ dst,
        const float* __restrict__ ew, int* __restrict__ cursor,
        int2* __restrict__ esw) {
    int i = blockIdx.x * blockDim.x + threadIdx.x;
    const int stride = gridDim.x * blockDim.x;
    for (; i < N_EDGES; i += stride) {
        int d   = dst[i];
        int pos = atomicAdd(&cursor[d], 1);
        esw[pos] = make_int2(src[i], __float_as_int(ew[i]));
    }
}

// ---------------------------------------------------------------------------
// Aggregate: one wave per dst row, NO atomics. Sums incident edge messages
// (coalesced 256B gathers of hs rows) and writes the normalized mean
// nv = acc / clip(sum_w, 1) once. end-of-row = cursor[d] (== rowptr[d+1]).
// ---------------------------------------------------------------------------
__global__ __launch_bounds__(256) void aggregate_kernel(
        const float* __restrict__ hs, const int2* __restrict__ esw,
        const int* __restrict__ rp, const int* __restrict__ cursor,
        float* __restrict__ nv) {
    const int lane = threadIdx.x & 63;
    const int d    = blockIdx.x * 4 + (threadIdx.x >> 6);
    if (d >= N_DST) return;
    int i = rp[d];
    const int e = cursor[d];
    float acc = 0.0f, ws = 0.0f;
    for (; i + 1 < e; i += 2) {                       // unroll-2 for MLP
        int2 p0 = esw[i], p1 = esw[i + 1];
        float w0 = __int_as_float(p0.y), w1 = __int_as_float(p1.y);
        float h0 = hs[p0.x * 64 + lane];
        float h1 = hs[p1.x * 64 + lane];
        acc = fmaf(h0, w0, acc);
        acc = fmaf(h1, w1, acc);
        ws += w0 + w1;
    }
    if (i < e) {
        int2 p = esw[i];
        float w0 = __int_as_float(p.y);
        acc = fmaf(hs[p.x * 64 + lane], w0, acc);
        ws += w0;
    }
    nv[d * 64 + lane] = acc / fmaxf(ws, 1.0f);
}

// ---------------------------------------------------------------------------
// Kernel fc2: new = relu(concat([nv, h_dst]) @ W2 + b2)
// (col-half ch, k-half kh) wave split; wcol[64] pinned in VGPRs via asm so
// the compiler cannot sink/rematerialize the invariant W2 loads into the
// row loop (round-2/3 failure mode). Partials combined through 8 KB LDS.
// ---------------------------------------------------------------------------
__global__ __launch_bounds__(256) void fc2_kernel(
        const float* __restrict__ nv, const float* __restrict__ h_dst,
        const float* __restrict__ W2, const float* __restrict__ b2,
        float* __restrict__ out, double* __restrict__ sumsq) {
    __shared__ float P[8 * 2 * 128];          // [row r][k-half][col], 8 KiB
    const int lane = threadIdx.x & 63;
    const int wid  = threadIdx.x >> 6;
    const int ch   = wid & 1;                 // column half
    const int kh   = wid >> 1;                // k half (0: nv part, 1: h_dst part)
    const float* __restrict__ xsrc = kh ? h_dst : nv;   // both [*, 64] row-major

    float wcol[64];                           // W2[kh*64+kk][ch*64+lane]
    #pragma unroll
    for (int kk = 0; kk < 64; ++kk)
        wcol[kk] = W2[(kh * 64 + kk) * OUT_F + ch * 64 + lane];
    #pragma unroll
    for (int kk = 0; kk < 64; ++kk)
        asm volatile("" : "+v"(wcol[kk]));    // pin: no sinking/remat into loop

    const float bias = b2[threadIdx.x & 127];
    double ss = 0.0;

    const int NG = N_DST / 8;                 // 12500 groups of 8 rows
    for (int g = blockIdx.x; g < NG; g += gridDim.x) {
        const int base = g * 8;
        float xr[8];
        #pragma unroll
        for (int r = 0; r < 8; ++r)
            xr[r] = xsrc[(base + r) * 64 + lane];
        #pragma unroll
        for (int r = 0; r < 8; ++r) {
            float a0 = 0.f, a1 = 0.f, a2 = 0.f, a3 = 0.f;
            #pragma unroll
            for (int kk = 0; kk < 64; kk += 4) {
                a0 = fmaf(__shfl(xr[r], kk,     64), wcol[kk],     a0);
                a1 = fmaf(__shfl(xr[r], kk + 1, 64), wcol[kk + 1], a1);
                a2 = fmaf(__shfl(xr[r], kk + 2, 64), wcol[kk + 2], a2);
                a3 = fmaf(__shfl(xr[r], kk + 3, 64), wcol[kk + 3], a3);
            }
            P[r * 256 + kh * 128 + ch * 64 + lane] = (a0 + a1) + (a2 + a3);
        }
        __syncthreads();
        #pragma unroll
        for (int v = 0; v < 4; ++v) {
            int idx = v * 256 + (int)threadIdx.x;
            int row = idx >> 7, col = idx & 127;
            float s = P[row * 256 + col] + P[row * 256 + 128 + col] + bias;
            float val = fmaxf(s, 0.0f);
            out[(base + row) * OUT_F + col] = val;
            ss += (double)val * (double)val;
        }
        __syncthreads();                      // WAR: P overwritten next round
    }
    #pragma unroll
    for (int off = 32; off > 0; off >>= 1) ss += __shfl_down(ss, off, 64);
    if (lane == 0) atomicAdd(sumsq, ss);
}

// ---------------------------------------------------------------------------
// Kernel: out *= 1/sqrt(sumsq)   (in-place, float4 grid-stride)
// ---------------------------------------------------------------------------
__global__ __launch_bounds__(256) void scale_kernel(
        float* __restrict__ out, const double* __restrict__ sumsq, int n4) {
    const float s = (float)(1.0 / sqrt(*sumsq));
    float4* o4 = (float4*)out;
    const int stride = gridDim.x * blockDim.x;
    for (int i = blockIdx.x * blockDim.x + threadIdx.x; i < n4; i += stride) {
        float4 v = o4[i];
        v.x *= s; v.y *= s; v.z *= s; v.w *= s;
        o4[i] = v;
    }
}

extern "C" void kernel_launch(void* const* d_in, const int* in_sizes, int n_in,
                              void* d_out, int out_size, void* d_ws, size_t ws_size,
                              hipStream_t stream) {
    const float* h_src = (const float*)d_in[0];
    const float* h_dst = (const float*)d_in[1];
    const float* ew    = (const float*)d_in[2];
    const float* W1    = (const float*)d_in[3];
    const float* b1    = (const float*)d_in[4];
    const float* W2    = (const float*)d_in[5];
    const float* b2    = (const float*)d_in[6];
    const int*   src   = (const int*)d_in[7];
    const int*   dst   = (const int*)d_in[8];
    float* out = (float*)d_out;

    // d_out (51.2 MB) doubles as scratch before fc2 rewrites it entirely:
    //   [0       , 25.6 MB) : hs               (dead after aggregate)
    //   [25.6 MB , 35.6 MB) : esw  int2[1.25M] (dead after aggregate)
    //   [35.6 MB , 36.0 MB) : rowptrA int[100k]  counts -> rowptr in place
    //   [36.0 MB , 36.4 MB) : cursor  int[100k]
    // d_ws:
    //   [0       , 25.6 MB) : nv   (live through fc2)
    //   [25.6 MB , +8 B   ) : sumsq
    float* hs      = out;
    int2*  esw     = (int2*)((char*)d_out + 25600000);
    int*   rowptrA = (int*)((char*)d_out + 35600000);
    int*   cursor  = (int*)((char*)d_out + 36000000);
    float* nv      = (float*)d_ws;
    double* sumsq  = (double*)((char*)d_ws + 25600000);

    hipMemsetAsync(rowptrA, 0, (size_t)N_DST * 4, stream);
    hipMemsetAsync(sumsq, 0, 8, stream);

    fc1_kernel<<<(N_SRC + 3) / 4, 256, 0, stream>>>(h_src, W1, b1, hs);
    hist_kernel<<<1024, 256, 0, stream>>>(dst, rowptrA);
    scan_kernel<<<1, 1024, 0, stream>>>(rowptrA, cursor);
    scatter_kernel<<<1024, 256, 0, stream>>>(src, dst, ew, cursor, esw);
    aggregate_kernel<<<(N_DST + 3) / 4, 256, 0, stream>>>(hs, esw, rowptrA, cursor, nv);
    fc2_kernel<<<1024, 256, 0, stream>>>(nv, h_dst, W2, b2, out, sumsq);
    scale_kernel<<<2048, 256, 0, stream>>>(out, sumsq, N_DST * OUT_F / 4);
}

// Round 5
// 614.898 us; speedup vs baseline: 1.6097x; 1.6097x over previous
//
#include <hip/hip_runtime.h>

#define N_SRC   100000
#define N_DST   100000
#define N_EDGES 1250000
#define D_FEAT  64
#define HIDDEN  64
#define OUT_F   128

// ---------------------------------------------------------------------------
// Kernel 1: hs = relu(h_src @ W1 + b1)   [N_SRC, 64]
// Wave per row (grid-stride). W1 column `lane` pinned in 64 VGPRs.
// x-row loaded via SCALAR loads (row index forced uniform with
// readfirstlane) -> inner loop is pure v_fmac with SGPR operand.
// No LDS, no shfl/ds_bpermute (round-4 lesson: bpermute broadcast was the
// latency wall).
// ---------------------------------------------------------------------------
__global__ __launch_bounds__(256) void fc1_kernel(
        const float* __restrict__ h_src, const float* __restrict__ W1,
        const float* __restrict__ b1, float* __restrict__ hs) {
    const int lane = threadIdx.x & 63;
    float wcol[64];                            // W1[k][lane]
    #pragma unroll
    for (int k = 0; k < 64; ++k) wcol[k] = W1[k * HIDDEN + lane];
    #pragma unroll
    for (int k = 0; k < 64; ++k) asm volatile("" : "+v"(wcol[k]));
    const float bias = b1[lane];
    const int wid    = blockIdx.x * 4 + (threadIdx.x >> 6);
    const int stride = gridDim.x * 4;
    for (int row = wid; row < N_SRC; row += stride) {
        const int urow = __builtin_amdgcn_readfirstlane(row);
        const float* __restrict__ xr = h_src + (size_t)urow * 64;
        float a0 = bias, a1 = 0.f, a2 = 0.f, a3 = 0.f;
        #pragma unroll
        for (int k = 0; k < 64; k += 4) {
            a0 = fmaf(xr[k],     wcol[k],     a0);   // xr[k] uniform -> s_load
            a1 = fmaf(xr[k + 1], wcol[k + 1], a1);
            a2 = fmaf(xr[k + 2], wcol[k + 2], a2);
            a3 = fmaf(xr[k + 3], wcol[k + 3], a3);
        }
        hs[(size_t)urow * 64 + lane] = fmaxf((a0 + a1) + (a2 + a3), 0.0f);
    }
}

// ---------------------------------------------------------------------------
// CSR build, step 1: histogram of dst.
// ---------------------------------------------------------------------------
__global__ __launch_bounds__(256) void hist_kernel(
        const int* __restrict__ dst, int* __restrict__ counts) {
    int i = blockIdx.x * blockDim.x + threadIdx.x;
    const int stride = gridDim.x * blockDim.x;
    for (; i < N_EDGES; i += stride) atomicAdd(&counts[dst[i]], 1);
}

// ---------------------------------------------------------------------------
// CSR build, step 2: single-block exclusive scan (counts -> rowptr) + copy
// into cursor[].
// ---------------------------------------------------------------------------
__global__ __launch_bounds__(1024) void scan_kernel(
        int* __restrict__ rp, int* __restrict__ cursor) {
    __shared__ int part[1024];
    const int t  = threadIdx.x;
    const int CH = (N_DST + 1023) / 1024;            // 98
    const int lo = t * CH;
    const int hi = min(lo + CH, N_DST);
    int s = 0;
    for (int i = lo; i < hi; ++i) s += rp[i];
    part[t] = s;
    __syncthreads();
    for (int off = 1; off < 1024; off <<= 1) {
        int v = part[t];
        int u = (t >= off) ? part[t - off] : 0;
        __syncthreads();
        part[t] = v + u;
        __syncthreads();
    }
    int running = (t == 0) ? 0 : part[t - 1];
    for (int i = lo; i < hi; ++i) {
        int c = rp[i];
        rp[i]     = running;
        cursor[i] = running;
        running  += c;
    }
}

// ---------------------------------------------------------------------------
// CSR build, step 3: scatter (src, weight) pairs into dst-sorted order.
// ---------------------------------------------------------------------------
__global__ __launch_bounds__(256) void scatter_kernel(
        const int* __restrict__ src, const int* __restrict__ dst,
        const float* __restrict__ ew, int* __restrict__ cursor,
        int2* __restrict__ esw) {
    int i = blockIdx.x * blockDim.x + threadIdx.x;
    const int stride = gridDim.x * blockDim.x;
    for (; i < N_EDGES; i += stride) {
        int d   = dst[i];
        int pos = atomicAdd(&cursor[d], 1);
        esw[pos] = make_int2(src[i], __float_as_int(ew[i]));
    }
}

// ---------------------------------------------------------------------------
// Aggregate: one wave per dst row, no atomics. Per-wave-uniform CSR walk:
// d forced to SGPR, so rp/cursor/esw loads are scalar; the hs row gather
// stays a coalesced 256B vector load. Writes nv = acc / clip(sum_w,1).
// ---------------------------------------------------------------------------
__global__ __launch_bounds__(256) void aggregate_kernel(
        const float* __restrict__ hs, const int2* __restrict__ esw,
        const int* __restrict__ rp, const int* __restrict__ cursor,
        float* __restrict__ nv) {
    const int lane = threadIdx.x & 63;
    const int d = __builtin_amdgcn_readfirstlane(blockIdx.x * 4 + (threadIdx.x >> 6));
    if (d >= N_DST) return;
    int i = rp[d];
    const int e = cursor[d];
    float acc = 0.0f, ws = 0.0f;
    for (; i + 1 < e; i += 2) {
        int2 p0 = esw[i], p1 = esw[i + 1];           // scalar loads (i uniform)
        float w0 = __int_as_float(p0.y), w1 = __int_as_float(p1.y);
        float h0 = hs[p0.x * 64 + lane];
        float h1 = hs[p1.x * 64 + lane];
        acc = fmaf(h0, w0, acc);
        acc = fmaf(h1, w1, acc);
        ws += w0 + w1;
    }
    if (i < e) {
        int2 p = esw[i];
        float w0 = __int_as_float(p.y);
        acc = fmaf(hs[p.x * 64 + lane], w0, acc);
        ws += w0;
    }
    nv[d * 64 + lane] = acc / fmaxf(ws, 1.0f);
}

// ---------------------------------------------------------------------------
// Kernel fc2: new = relu(concat([nv, h_dst]) @ W2 + b2)
// (col-half ch, k-half kh) wave split; wcol[64] pinned in VGPRs (validated
// round 4: VGPR=80, FETCH ideal). x values now read via SCALAR loads
// (kh made uniform via readfirstlane; group base already uniform) ->
// inner loop = pure v_fmac with SGPR broadcast, zero DS ops.
// Partials combined through 8 KB LDS (+bias, relu, store, sum-of-squares).
// ---------------------------------------------------------------------------
__global__ __launch_bounds__(256) void fc2_kernel(
        const float* __restrict__ nv, const float* __restrict__ h_dst,
        const float* __restrict__ W2, const float* __restrict__ b2,
        float* __restrict__ out, double* __restrict__ sumsq) {
    __shared__ float P[8 * 2 * 128];          // [row r][k-half][col], 8 KiB
    const int lane = threadIdx.x & 63;
    const int wid  = threadIdx.x >> 6;
    const int ch   = wid & 1;                 // column half
    const int khu  = __builtin_amdgcn_readfirstlane(wid >> 1);   // k half, uniform
    const float* __restrict__ xsrc = khu ? h_dst : nv;           // uniform ptr

    float wcol[64];                           // W2[khu*64+kk][ch*64+lane]
    #pragma unroll
    for (int kk = 0; kk < 64; ++kk)
        wcol[kk] = W2[(khu * 64 + kk) * OUT_F + ch * 64 + lane];
    #pragma unroll
    for (int kk = 0; kk < 64; ++kk)
        asm volatile("" : "+v"(wcol[kk]));    // pin: no sinking/remat into loop

    const float bias = b2[threadIdx.x & 127];
    double ss = 0.0;

    const int NG = N_DST / 8;                 // 12500 groups of 8 rows
    for (int g = blockIdx.x; g < NG; g += gridDim.x) {
        const int base = g * 8;               // uniform (blockIdx-derived)
        #pragma unroll
        for (int r = 0; r < 8; ++r) {
            const float* __restrict__ xr = xsrc + (size_t)(base + r) * 64;
            float a0 = 0.f, a1 = 0.f, a2 = 0.f, a3 = 0.f;
            #pragma unroll
            for (int kk = 0; kk < 64; kk += 4) {
                a0 = fmaf(xr[kk],     wcol[kk],     a0);   // s_load broadcast
                a1 = fmaf(xr[kk + 1], wcol[kk + 1], a1);
                a2 = fmaf(xr[kk + 2], wcol[kk + 2], a2);
                a3 = fmaf(xr[kk + 3], wcol[kk + 3], a3);
            }
            P[r * 256 + khu * 128 + ch * 64 + lane] = (a0 + a1) + (a2 + a3);
        }
        __syncthreads();
        #pragma unroll
        for (int v = 0; v < 4; ++v) {
            int idx = v * 256 + (int)threadIdx.x;
            int row = idx >> 7, col = idx & 127;
            float s = P[row * 256 + col] + P[row * 256 + 128 + col] + bias;
            float val = fmaxf(s, 0.0f);
            out[(base + row) * OUT_F + col] = val;
            ss += (double)val * (double)val;
        }
        __syncthreads();                      // WAR: P overwritten next round
    }
    #pragma unroll
    for (int off = 32; off > 0; off >>= 1) ss += __shfl_down(ss, off, 64);
    if (lane == 0) atomicAdd(sumsq, ss);
}

// ---------------------------------------------------------------------------
// Kernel: out *= 1/sqrt(sumsq)   (in-place, float4 grid-stride)
// ---------------------------------------------------------------------------
__global__ __launch_bounds__(256) void scale_kernel(
        float* __restrict__ out, const double* __restrict__ sumsq, int n4) {
    const float s = (float)(1.0 / sqrt(*sumsq));
    float4* o4 = (float4*)out;
    const int stride = gridDim.x * blockDim.x;
    for (int i = blockIdx.x * blockDim.x + threadIdx.x; i < n4; i += stride) {
        float4 v = o4[i];
        v.x *= s; v.y *= s; v.z *= s; v.w *= s;
        o4[i] = v;
    }
}

extern "C" void kernel_launch(void* const* d_in, const int* in_sizes, int n_in,
                              void* d_out, int out_size, void* d_ws, size_t ws_size,
                              hipStream_t stream) {
    const float* h_src = (const float*)d_in[0];
    const float* h_dst = (const float*)d_in[1];
    const float* ew    = (const float*)d_in[2];
    const float* W1    = (const float*)d_in[3];
    const float* b1    = (const float*)d_in[4];
    const float* W2    = (const float*)d_in[5];
    const float* b2    = (const float*)d_in[6];
    const int*   src   = (const int*)d_in[7];
    const int*   dst   = (const int*)d_in[8];
    float* out = (float*)d_out;

    // d_out (51.2 MB) doubles as scratch before fc2 rewrites it entirely:
    //   [0       , 25.6 MB) : hs               (dead after aggregate)
    //   [25.6 MB , 35.6 MB) : esw  int2[1.25M] (dead after aggregate)
    //   [35.6 MB , 36.0 MB) : rowptrA int[100k]  counts -> rowptr in place
    //   [36.0 MB , 36.4 MB) : cursor  int[100k]
    // d_ws:
    //   [0       , 25.6 MB) : nv   (live through fc2)
    //   [25.6 MB , +8 B   ) : sumsq
    float* hs      = out;
    int2*  esw     = (int2*)((char*)d_out + 25600000);
    int*   rowptrA = (int*)((char*)d_out + 35600000);
    int*   cursor  = (int*)((char*)d_out + 36000000);
    float* nv      = (float*)d_ws;
    double* sumsq  = (double*)((char*)d_ws + 25600000);

    hipMemsetAsync(rowptrA, 0, (size_t)N_DST * 4, stream);
    hipMemsetAsync(sumsq, 0, 8, stream);

    fc1_kernel<<<2048, 256, 0, stream>>>(h_src, W1, b1, hs);
    hist_kernel<<<1024, 256, 0, stream>>>(dst, rowptrA);
    scan_kernel<<<1, 1024, 0, stream>>>(rowptrA, cursor);
    scatter_kernel<<<1024, 256, 0, stream>>>(src, dst, ew, cursor, esw);
    aggregate_kernel<<<(N_DST + 3) / 4, 256, 0, stream>>>(hs, esw, rowptrA, cursor, nv);
    fc2_kernel<<<2048, 256, 0, stream>>>(nv, h_dst, W2, b2, out, sumsq);
    scale_kernel<<<2048, 256, 0, stream>>>(out, sumsq, N_DST * OUT_F / 4);
}

// Round 6
// 405.307 us; speedup vs baseline: 2.4421x; 1.5171x over previous
//
#include <hip/hip_runtime.h>

#define N_SRC   100000
#define N_DST   100000
#define N_EDGES 1250000
#define D_FEAT  64
#define HIDDEN  64
#define OUT_F   128

#define NB_SCAN 196   // ceil(N_DST / 512); each scan block owns 512 counts

// ---------------------------------------------------------------------------
// Kernel 1: hs = relu(h_src @ W1 + b1)   [N_SRC, 64]
// Wave per row (grid-stride). W1 column `lane` pinned in 64 VGPRs; x-row via
// scalar loads (uniform row) -> pure v_fmac with SGPR broadcast.
// ---------------------------------------------------------------------------
__global__ __launch_bounds__(256) void fc1_kernel(
        const float* __restrict__ h_src, const float* __restrict__ W1,
        const float* __restrict__ b1, float* __restrict__ hs) {
    const int lane = threadIdx.x & 63;
    float wcol[64];                            // W1[k][lane]
    #pragma unroll
    for (int k = 0; k < 64; ++k) wcol[k] = W1[k * HIDDEN + lane];
    #pragma unroll
    for (int k = 0; k < 64; ++k) asm volatile("" : "+v"(wcol[k]));
    const float bias = b1[lane];
    const int wid    = blockIdx.x * 4 + (threadIdx.x >> 6);
    const int stride = gridDim.x * 4;
    for (int row = wid; row < N_SRC; row += stride) {
        const int urow = __builtin_amdgcn_readfirstlane(row);
        const float* __restrict__ xr = h_src + (size_t)urow * 64;
        float a0 = bias, a1 = 0.f, a2 = 0.f, a3 = 0.f;
        #pragma unroll
        for (int k = 0; k < 64; k += 4) {
            a0 = fmaf(xr[k],     wcol[k],     a0);
            a1 = fmaf(xr[k + 1], wcol[k + 1], a1);
            a2 = fmaf(xr[k + 2], wcol[k + 2], a2);
            a3 = fmaf(xr[k + 3], wcol[k + 3], a3);
        }
        hs[(size_t)urow * 64 + lane] = fmaxf((a0 + a1) + (a2 + a3), 0.0f);
    }
}

// ---------------------------------------------------------------------------
// CSR build, step 1: histogram of dst.
// ---------------------------------------------------------------------------
__global__ __launch_bounds__(256) void hist_kernel(
        const int* __restrict__ dst, int* __restrict__ counts) {
    int i = blockIdx.x * blockDim.x + threadIdx.x;
    const int stride = gridDim.x * blockDim.x;
    for (; i < N_EDGES; i += stride) atomicAdd(&counts[dst[i]], 1);
}

// ---------------------------------------------------------------------------
// CSR scan phase A: per-block sums (196 blocks x 512 counts, int2 loads).
// ---------------------------------------------------------------------------
__global__ __launch_bounds__(256) void scan_bsum_kernel(
        const int* __restrict__ c, int* __restrict__ bsum) {
    const int t  = threadIdx.x;
    const int i0 = blockIdx.x * 512 + 2 * t;
    int v0 = (i0     < N_DST) ? c[i0]     : 0;
    int v1 = (i0 + 1 < N_DST) ? c[i0 + 1] : 0;
    int s = v0 + v1;
    #pragma unroll
    for (int off = 32; off > 0; off >>= 1) s += __shfl_down(s, off, 64);
    __shared__ int ws[4];
    if ((t & 63) == 0) ws[t >> 6] = s;
    __syncthreads();
    if (t == 0) bsum[blockIdx.x] = ws[0] + ws[1] + ws[2] + ws[3];
}

// ---------------------------------------------------------------------------
// CSR scan phase B: single small block — exclusive scan of the 196 sums.
// ---------------------------------------------------------------------------
__global__ __launch_bounds__(256) void scan_boff_kernel(
        const int* __restrict__ bsum, int* __restrict__ boff) {
    const int t = threadIdx.x, lane = t & 63, w = t >> 6;
    int v = (t < NB_SCAN) ? bsum[t] : 0;
    int inc = v;
    #pragma unroll
    for (int off = 1; off < 64; off <<= 1) {
        int u = __shfl_up(inc, off, 64);
        if (lane >= off) inc += u;
    }
    __shared__ int wsum[4];
    if (lane == 63) wsum[w] = inc;
    __syncthreads();
    int add = 0;
    for (int i = 0; i < w; ++i) add += wsum[i];
    if (t < NB_SCAN) boff[t] = add + inc - v;
}

// ---------------------------------------------------------------------------
// CSR scan phase C: re-read counts, in-block exclusive scan + boff, write
// rowptr and cursor (in place over counts — each element is read then
// written by exactly one thread).
// ---------------------------------------------------------------------------
__global__ __launch_bounds__(256) void scan_write_kernel(
        const int* __restrict__ boff, int* __restrict__ c,
        int* __restrict__ cursor) {
    const int t = threadIdx.x, lane = t & 63, w = t >> 6;
    const int i0 = blockIdx.x * 512 + 2 * t;
    int v0 = (i0     < N_DST) ? c[i0]     : 0;
    int v1 = (i0 + 1 < N_DST) ? c[i0 + 1] : 0;
    int s = v0 + v1;
    int inc = s;
    #pragma unroll
    for (int off = 1; off < 64; off <<= 1) {
        int u = __shfl_up(inc, off, 64);
        if (lane >= off) inc += u;
    }
    __shared__ int wsum[4];
    if (lane == 63) wsum[w] = inc;
    __syncthreads();
    int add = boff[blockIdx.x];
    for (int i = 0; i < w; ++i) add += wsum[i];
    int g = add + inc - s;                       // exclusive offset of i0
    if (i0 < N_DST)     { c[i0]     = g;      cursor[i0]     = g; }
    if (i0 + 1 < N_DST) { c[i0 + 1] = g + v0; cursor[i0 + 1] = g + v0; }
}

// ---------------------------------------------------------------------------
// CSR build, step 3: scatter (src, weight) pairs into dst-sorted order.
// ---------------------------------------------------------------------------
__global__ __launch_bounds__(256) void scatter_kernel(
        const int* __restrict__ src, const int* __restrict__ dst,
        const float* __restrict__ ew, int* __restrict__ cursor,
        int2* __restrict__ esw) {
    int i = blockIdx.x * blockDim.x + threadIdx.x;
    const int stride = gridDim.x * blockDim.x;
    for (; i < N_EDGES; i += stride) {
        int d   = dst[i];
        int pos = atomicAdd(&cursor[d], 1);
        esw[pos] = make_int2(src[i], __float_as_int(ew[i]));
    }
}

// ---------------------------------------------------------------------------
// Aggregate: one wave per dst row, no atomics; uniform CSR walk (scalar
// loads for esw/rp/cursor), coalesced 256B hs-row gathers.
// ---------------------------------------------------------------------------
__global__ __launch_bounds__(256) void aggregate_kernel(
        const float* __restrict__ hs, const int2* __restrict__ esw,
        const int* __restrict__ rp, const int* __restrict__ cursor,
        float* __restrict__ nv) {
    const int lane = threadIdx.x & 63;
    const int d = __builtin_amdgcn_readfirstlane(blockIdx.x * 4 + (threadIdx.x >> 6));
    if (d >= N_DST) return;
    int i = rp[d];
    const int e = cursor[d];
    float acc = 0.0f, ws = 0.0f;
    for (; i + 1 < e; i += 2) {
        int2 p0 = esw[i], p1 = esw[i + 1];
        float w0 = __int_as_float(p0.y), w1 = __int_as_float(p1.y);
        float h0 = hs[p0.x * 64 + lane];
        float h1 = hs[p1.x * 64 + lane];
        acc = fmaf(h0, w0, acc);
        acc = fmaf(h1, w1, acc);
        ws += w0 + w1;
    }
    if (i < e) {
        int2 p = esw[i];
        float w0 = __int_as_float(p.y);
        acc = fmaf(hs[p.x * 64 + lane], w0, acc);
        ws += w0;
    }
    nv[d * 64 + lane] = acc / fmaxf(ws, 1.0f);
}

// ---------------------------------------------------------------------------
// Kernel fc2: new = relu(concat([nv, h_dst]) @ W2 + b2)
// (ch, kh) wave split; wcol[64] pinned in VGPRs; scalar-broadcast x.
// ---------------------------------------------------------------------------
__global__ __launch_bounds__(256) void fc2_kernel(
        const float* __restrict__ nv, const float* __restrict__ h_dst,
        const float* __restrict__ W2, const float* __restrict__ b2,
        float* __restrict__ out, double* __restrict__ sumsq) {
    __shared__ float P[8 * 2 * 128];          // [row r][k-half][col], 8 KiB
    const int lane = threadIdx.x & 63;
    const int wid  = threadIdx.x >> 6;
    const int ch   = wid & 1;
    const int khu  = __builtin_amdgcn_readfirstlane(wid >> 1);
    const float* __restrict__ xsrc = khu ? h_dst : nv;

    float wcol[64];                           // W2[khu*64+kk][ch*64+lane]
    #pragma unroll
    for (int kk = 0; kk < 64; ++kk)
        wcol[kk] = W2[(khu * 64 + kk) * OUT_F + ch * 64 + lane];
    #pragma unroll
    for (int kk = 0; kk < 64; ++kk)
        asm volatile("" : "+v"(wcol[kk]));

    const float bias = b2[threadIdx.x & 127];
    double ss = 0.0;

    const int NG = N_DST / 8;                 // 12500 groups of 8 rows
    for (int g = blockIdx.x; g < NG; g += gridDim.x) {
        const int base = g * 8;
        #pragma unroll
        for (int r = 0; r < 8; ++r) {
            const float* __restrict__ xr = xsrc + (size_t)(base + r) * 64;
            float a0 = 0.f, a1 = 0.f, a2 = 0.f, a3 = 0.f;
            #pragma unroll
            for (int kk = 0; kk < 64; kk += 4) {
                a0 = fmaf(xr[kk],     wcol[kk],     a0);
                a1 = fmaf(xr[kk + 1], wcol[kk + 1], a1);
                a2 = fmaf(xr[kk + 2], wcol[kk + 2], a2);
                a3 = fmaf(xr[kk + 3], wcol[kk + 3], a3);
            }
            P[r * 256 + khu * 128 + ch * 64 + lane] = (a0 + a1) + (a2 + a3);
        }
        __syncthreads();
        #pragma unroll
        for (int v = 0; v < 4; ++v) {
            int idx = v * 256 + (int)threadIdx.x;
            int row = idx >> 7, col = idx & 127;
            float s = P[row * 256 + col] + P[row * 256 + 128 + col] + bias;
            float val = fmaxf(s, 0.0f);
            out[(base + row) * OUT_F + col] = val;
            ss += (double)val * (double)val;
        }
        __syncthreads();
    }
    #pragma unroll
    for (int off = 32; off > 0; off >>= 1) ss += __shfl_down(ss, off, 64);
    if (lane == 0) atomicAdd(sumsq, ss);
}

// ---------------------------------------------------------------------------
// Kernel: out *= 1/sqrt(sumsq)   (in-place, float4 grid-stride)
// ---------------------------------------------------------------------------
__global__ __launch_bounds__(256) void scale_kernel(
        float* __restrict__ out, const double* __restrict__ sumsq, int n4) {
    const float s = (float)(1.0 / sqrt(*sumsq));
    float4* o4 = (float4*)out;
    const int stride = gridDim.x * blockDim.x;
    for (int i = blockIdx.x * blockDim.x + threadIdx.x; i < n4; i += stride) {
        float4 v = o4[i];
        v.x *= s; v.y *= s; v.z *= s; v.w *= s;
        o4[i] = v;
    }
}

extern "C" void kernel_launch(void* const* d_in, const int* in_sizes, int n_in,
                              void* d_out, int out_size, void* d_ws, size_t ws_size,
                              hipStream_t stream) {
    const float* h_src = (const float*)d_in[0];
    const float* h_dst = (const float*)d_in[1];
    const float* ew    = (const float*)d_in[2];
    const float* W1    = (const float*)d_in[3];
    const float* b1    = (const float*)d_in[4];
    const float* W2    = (const float*)d_in[5];
    const float* b2    = (const float*)d_in[6];
    const int*   src   = (const int*)d_in[7];
    const int*   dst   = (const int*)d_in[8];
    float* out = (float*)d_out;

    // d_out (51.2 MB) doubles as scratch before fc2 rewrites it entirely:
    //   [0       , 25.6 MB) : hs               (dead after aggregate)
    //   [25.6 MB , 35.6 MB) : esw  int2[1.25M] (dead after aggregate)
    //   [35.6 MB , 36.0 MB) : rowptrA int[100k]  counts -> rowptr in place
    //   [36.0 MB , 36.4 MB) : cursor  int[100k]
    //   [36.4 MB , +~1 KB ) : bsum[196], boff[196]
    // d_ws:
    //   [0       , 25.6 MB) : nv   (live through fc2)
    //   [25.6 MB , +8 B   ) : sumsq
    float* hs      = out;
    int2*  esw     = (int2*)((char*)d_out + 25600000);
    int*   rowptrA = (int*)((char*)d_out + 35600000);
    int*   cursor  = (int*)((char*)d_out + 36000000);
    int*   bsum    = (int*)((char*)d_out + 36400000);
    int*   boff    = bsum + 256;
    float* nv      = (float*)d_ws;
    double* sumsq  = (double*)((char*)d_ws + 25600000);

    hipMemsetAsync(rowptrA, 0, (size_t)N_DST * 4, stream);
    hipMemsetAsync(sumsq, 0, 8, stream);

    fc1_kernel<<<2048, 256, 0, stream>>>(h_src, W1, b1, hs);
    hist_kernel<<<1024, 256, 0, stream>>>(dst, rowptrA);
    scan_bsum_kernel<<<NB_SCAN, 256, 0, stream>>>(rowptrA, bsum);
    scan_boff_kernel<<<1, 256, 0, stream>>>(bsum, boff);
    scan_write_kernel<<<NB_SCAN, 256, 0, stream>>>(boff, rowptrA, cursor);
    scatter_kernel<<<1024, 256, 0, stream>>>(src, dst, ew, cursor, esw);
    aggregate_kernel<<<(N_DST + 3) / 4, 256, 0, stream>>>(hs, esw, rowptrA, cursor, nv);
    fc2_kernel<<<2048, 256, 0, stream>>>(nv, h_dst, W2, b2, out, sumsq);
    scale_kernel<<<2048, 256, 0, stream>>>(out, sumsq, N_DST * OUT_F / 4);
}